// Round 18
// baseline (518.709 us; speedup 1.0000x reference)
//
#include <hip/hip_runtime.h>

// ResidualVQ: B=8, T=2048, D=256, Q=8, K=1024. N = B*T = 16384.
// Scoring via fp16 split-MFMA: 2x = xh + xl, e = eh + el (fp16 RTNE).
// 2x.e ~= xh.eh + xh.el + xl.eh  (dropped xl.el ~ 2e-6, below fp32 noise).
// score = acc - |e|^2  (row-constant |x|^2 dropped; same argmax).
//
// ROUND 18 = round 17 (verified 284us) with ONE change: A (ecat) loads
// global->register instead of global->LDS->register. Byte-verified identity:
// r17's LDS path delivers ecat row (p*256+wcq*64+m*32+l32), col
// (c*32+kh*16+lh*8); the direct load reads exactly that address, and the
// MFMA order is kept instruction-for-instruction -> scores bitwise equal
// to r17 -> identical argmax. Eliminates: all GEMM barriers + vmcnt drains
// (sB read-only per layer), the staging pipeline, and 2/3 of LDS traffic.
// ecat layer slice (1 MB) is L2-resident; per-wave A working set is
// L1-friendly (wt-pair waves share lines). Unlike failed r15, wave map /
// merge / B path / update are UNTOUCHED.
//
// d_out (float): [0, N*D) quantized_out; [N*D,+Q*N) indices; [+Q) losses
// d_ws: ecat f16[Q*K][512] | norms f32[Q*K]

typedef _Float16 f16;
typedef f16 f16x8 __attribute__((ext_vector_type(8)));
typedef float f32x16 __attribute__((ext_vector_type(16)));

constexpr int Dd = 256;
constexpr int Kk = 1024;
constexpr int Qq = 8;
constexpr int Nn = 16384;

// ---- build ecat[Q*K][512] = [eh|el] + squared norms, from fp32 codebooks ----
__global__ __launch_bounds__(256) void build_ecat(const float* __restrict__ cb,
                                                  f16* __restrict__ ecat,
                                                  float* __restrict__ norms) {
    int row = blockIdx.x * 8 + (threadIdx.x >> 5);
    int p = threadIdx.x & 31;
    const float* s = cb + (size_t)row * Dd + p * 8;
    f16x8 hi, lo;
    float sq = 0.f;
#pragma unroll
    for (int j = 0; j < 8; ++j) {
        float v = s[j];
        f16 h = (f16)v;
        hi[j] = h; lo[j] = (f16)(v - (float)h);
        sq = fmaf(v, v, sq);
    }
    *(f16x8*)(ecat + (size_t)row * 512 + p * 8) = hi;
    *(f16x8*)(ecat + (size_t)row * 512 + 256 + p * 8) = lo;
#pragma unroll
    for (int off = 16; off >= 1; off >>= 1) sq += __shfl_down(sq, off, 32);
    if (p == 0) norms[row] = sq;
}

// ---- the whole RVQ, one launch: block = 64 tokens through all 8 layers ----
__global__ __launch_bounds__(512, 2) void rvq_kernel(
    const float* __restrict__ x,      // [N][256]
    const float* __restrict__ cbs,    // [Q][K][256] fp32
    const f16* __restrict__ ecat,     // [Q*K][512]
    const float* __restrict__ norms,  // [Q*K]
    float* __restrict__ outq,         // d_out [N][256]
    float* __restrict__ idxs,         // d_out [Q][N] (as float)
    float* __restrict__ losses)       // d_out [Q]
{
    __shared__ f16 sB[32768];         // 16 sub-tiles [64r][32c]: 0-7 xh, 8-15 xl
    __shared__ float smn[1024];
    __shared__ float2 smg[4][64];
    __shared__ int bestk[64];
    __shared__ float lred[8];

    const int tid = threadIdx.x;
    const int w = tid >> 6, l = tid & 63;
    const int l32 = l & 31, lh = l >> 5;
    const int wcq = w >> 1;           // code quad 0..3 (64 codes each per pass)
    const int wt = w & 1;             // token half 0..1 (32 tokens each)
    const int tbase = blockIdx.x * 64;
    const int ut = tid >> 3, ud = tid & 7;   // token 0..63, dim-group 0..7
    const int grow = tbase + ut;

    // B ds_read offsets (r17): slot = (kh*2+lh) ^ ((row>>3)&3) ^ (c&3);
    // c is compile-time in the unrolled loop -> constant index into rbh.
    int rbh[4][2];
#pragma unroll
    for (int cc = 0; cc < 4; ++cc)
#pragma unroll
        for (int kh = 0; kh < 2; ++kh) {
            int row = wt * 32 + l32;
            rbh[cc][kh] = row * 32 + ((((kh * 2 + lh) ^ ((row >> 3) & 3)) ^ cc) * 8);
        }

    float r[32];   // residual: token ut, dims ud*32 .. ud*32+31

#pragma unroll 1
    for (int q = 0; q < Qq; ++q) {
        // ---- update phase (residual in registers) ----
        float lp = 0.f;
        if (q == 0) {
            const float4* xs = (const float4*)(x + (size_t)grow * Dd + ud * 32);
#pragma unroll
            for (int jv = 0; jv < 8; ++jv) {
                float4 v = xs[jv];
                r[jv * 4 + 0] = v.x; r[jv * 4 + 1] = v.y;
                r[jv * 4 + 2] = v.z; r[jv * 4 + 3] = v.w;
            }
        } else {
            const int k = bestk[ut];
            const float4* e4 = (const float4*)(cbs + ((size_t)(q - 1) * Kk + k) * Dd + ud * 32);
#pragma unroll
            for (int jv = 0; jv < 8; ++jv) {
                float4 v = e4[jv];
                r[jv * 4 + 0] -= v.x; r[jv * 4 + 1] -= v.y;
                r[jv * 4 + 2] -= v.z; r[jv * 4 + 3] -= v.w;
            }
#pragma unroll
            for (int j = 0; j < 32; ++j) lp = fmaf(r[j], r[j], lp);
            if ((tid & 7) == 0) idxs[(size_t)(q - 1) * Nn + grow] = (float)k;
#pragma unroll
            for (int off = 32; off >= 1; off >>= 1) lp += __shfl_down(lp, off);
            if (l == 0) lred[w] = lp;
        }
        // ---- build B tile in LDS: split(2r) -> xh sub-tile ud, xl 8+ud.
        //      qd compile-time (rule #20); lane spread via slot ^= (ud&3).
        {
            const int s = (ut >> 3) & 3;
#pragma unroll
            for (int qd = 0; qd < 4; ++qd) {
                f16x8 hi, lo;
#pragma unroll
                for (int j2 = 0; j2 < 8; ++j2) {
                    float v = 2.f * r[qd * 8 + j2];
                    f16 h = (f16)v;
                    hi[j2] = h; lo[j2] = (f16)(v - (float)h);
                }
                int a = ud * 2048 + ut * 32 + ((((qd ^ s) ^ (ud & 3)) & 3) * 8);
                *(f16x8*)&sB[a] = hi;
                *(f16x8*)&sB[16384 + a] = lo;
            }
        }
        smn[tid] = norms[q * Kk + tid];
        smn[512 + tid] = norms[q * Kk + 512 + tid];
        __syncthreads();   // sB + smn visible; bestk consumed
        if (q > 0 && tid == 0) {
            float s2 = 0.f;
#pragma unroll
            for (int i = 0; i < 8; ++i) s2 += lred[i];
            atomicAdd(losses + q - 1, s2 * (1.0f / ((float)Nn * (float)Dd)));
        }

        // ---- GEMM: 4 passes x 256 codes; A direct global->reg (no barriers) ----
        float bv = -3.4e38f; int bi = 0;
#pragma unroll 1
        for (int p = 0; p < 4; ++p) {
            // A rows for this wave: p*256 + wcq*64 + m*32 + l32; col lh*8 base.
            const f16* a0p = ecat + ((size_t)q * Kk + p * 256 + wcq * 64 + l32) * 512 + lh * 8;
            const f16* a1p = a0p + (size_t)32 * 512;

            f32x16 acc[2] = {};
            f16x8 fa0[2], fa1[2], fe0[2], fe1[2], fbh[2], fbl[2];

#define LOADF(S, IDX) do { \
            const int c_ = (IDX) >> 1, kh_ = (IDX) & 1; \
            const int co_ = c_ * 32 + kh_ * 16; \
            fa0[S] = *(const f16x8*)(a0p + co_); \
            fa1[S] = *(const f16x8*)(a1p + co_); \
            fe0[S] = *(const f16x8*)(a0p + 256 + co_); \
            fe1[S] = *(const f16x8*)(a1p + 256 + co_); \
            fbh[S] = *(const f16x8*)&sB[c_ * 2048 + rbh[c_ & 3][kh_]]; \
            fbl[S] = *(const f16x8*)&sB[16384 + c_ * 2048 + rbh[c_ & 3][kh_]]; \
        } while (0)

            LOADF(0, 0);
#pragma unroll
            for (int idx = 0; idx < 16; ++idx) {
                const int cur = idx & 1;
                if (idx < 15) LOADF(cur ^ 1, idx + 1);
                __builtin_amdgcn_s_setprio(1);
                acc[0] = __builtin_amdgcn_mfma_f32_32x32x16_f16(fa0[cur], fbh[cur], acc[0], 0, 0, 0);
                acc[1] = __builtin_amdgcn_mfma_f32_32x32x16_f16(fa1[cur], fbh[cur], acc[1], 0, 0, 0);
                acc[0] = __builtin_amdgcn_mfma_f32_32x32x16_f16(fa0[cur], fbl[cur], acc[0], 0, 0, 0);
                acc[1] = __builtin_amdgcn_mfma_f32_32x32x16_f16(fa1[cur], fbl[cur], acc[1], 0, 0, 0);
                acc[0] = __builtin_amdgcn_mfma_f32_32x32x16_f16(fe0[cur], fbh[cur], acc[0], 0, 0, 0);
                acc[1] = __builtin_amdgcn_mfma_f32_32x32x16_f16(fe1[cur], fbh[cur], acc[1], 0, 0, 0);
                __builtin_amdgcn_s_setprio(0);
            }
#undef LOADF

            // epilogue: score = acc - |e|^2 ; ascending code order (r17 verbatim)
#pragma unroll
            for (int m = 0; m < 2; ++m) {
#pragma unroll
                for (int rr = 0; rr < 16; ++rr) {
                    int cl = wcq * 64 + m * 32 + (rr & 3) + 8 * (rr >> 2) + 4 * lh;
                    float v = acc[m][rr] - smn[p * 256 + cl];
                    int cg = p * 256 + cl;
                    if (v > bv) { bv = v; bi = cg; }
                }
            }
        }
        // ---- merge: lanes l<->l^32 (same token), then the 4 code-quad waves ----
        {
            float ov = __shfl_xor(bv, 32);
            int oi = __shfl_xor(bi, 32);
            if (ov > bv || (ov == bv && oi < bi)) { bv = ov; bi = oi; }
            if (l < 32) smg[wcq][wt * 32 + l] = make_float2(bv, (float)bi);
            __syncthreads();
            if (tid < 64) {
                float2 r2 = smg[0][tid];
#pragma unroll
                for (int ww = 1; ww < 4; ++ww) {
                    float2 c2 = smg[ww][tid];
                    if (c2.x > r2.x || (c2.x == r2.x && c2.y < r2.y)) r2 = c2;
                }
                bestk[tid] = (int)r2.y;
            }
            __syncthreads();
        }
    }

    // ---- final: subtract e7, loss7, idx7, out = x - r8 ----
    {
        const int k = bestk[ut];
        const float4* e4 = (const float4*)(cbs + ((size_t)7 * Kk + k) * Dd + ud * 32);
        float lp = 0.f;
#pragma unroll
        for (int jv = 0; jv < 8; ++jv) {
            float4 v = e4[jv];
            r[jv * 4 + 0] -= v.x; r[jv * 4 + 1] -= v.y;
            r[jv * 4 + 2] -= v.z; r[jv * 4 + 3] -= v.w;
        }
#pragma unroll
        for (int j = 0; j < 32; ++j) lp = fmaf(r[j], r[j], lp);
        const float4* xs = (const float4*)(x + (size_t)grow * Dd + ud * 32);
        float4* os = (float4*)(outq + (size_t)grow * Dd + ud * 32);
#pragma unroll
        for (int jv = 0; jv < 8; ++jv) {
            float4 xv = xs[jv];
            float4 o;
            o.x = xv.x - r[jv * 4 + 0]; o.y = xv.y - r[jv * 4 + 1];
            o.z = xv.z - r[jv * 4 + 2]; o.w = xv.w - r[jv * 4 + 3];
            os[jv] = o;
        }
        if ((tid & 7) == 0) idxs[(size_t)7 * Nn + grow] = (float)k;
#pragma unroll
        for (int off = 32; off >= 1; off >>= 1) lp += __shfl_down(lp, off);
        if (l == 0) lred[w] = lp;
        __syncthreads();
        if (tid == 0) {
            float s2 = 0.f;
#pragma unroll
            for (int i = 0; i < 8; ++i) s2 += lred[i];
            atomicAdd(losses + 7, s2 * (1.0f / ((float)Nn * (float)Dd)));
        }
    }
}

extern "C" void kernel_launch(void* const* d_in, const int* in_sizes, int n_in,
                              void* d_out, int out_size, void* d_ws, size_t ws_size,
                              hipStream_t stream) {
    const float* x   = (const float*)d_in[0];   // [N,D]
    const float* cbs = (const float*)d_in[1];   // [Q,K,D]
    float* out    = (float*)d_out;
    float* idxs   = out + (size_t)Nn * Dd;        // [Q*N]
    float* losses = idxs + (size_t)Qq * Nn;       // [Q]

    f16* ecat    = (f16*)d_ws;                          // [Q*K][512]
    float* norms = (float*)(ecat + (size_t)Qq * Kk * 512);  // [Q*K]

    hipMemsetAsync(losses, 0, Qq * sizeof(float), stream);
    build_ecat<<<(Qq * Kk) / 8, 256, 0, stream>>>(cbs, ecat, norms);
    rvq_kernel<<<Nn / 64, 512, 0, stream>>>(x, cbs, ecat, norms,
                                            out, idxs, losses);
}

// Round 19
// 334.419 us; speedup vs baseline: 1.5511x; 1.5511x over previous
//
#include <hip/hip_runtime.h>

// ResidualVQ: B=8, T=2048, D=256, Q=8, K=1024. N = B*T = 16384.
// Scoring via fp16 split-MFMA: 2x = xh + xl, e = eh + el (fp16 RTNE).
// 2x.e ~= xh.eh + xh.el + xl.eh  (dropped xl.el ~ 2e-6, below fp32 noise).
// score = acc - |e|^2  (row-constant |x|^2 dropped; same argmax).
//
// ROUND 19 = r17 (verified 284us) at 1024 threads (16 waves = 4/SIMD):
// r17 was latency/lockstep-bound (MfmaUtil 29 + VALU 14 = 43% busy, LDS pipe
// ~50%; 2 waves/SIMD). Same 64-token block, same per-CU traffic, 2x waves:
// 2 passes x 512 codes, wave = 64 codes x 32 tokens (r17 fragment pattern),
// half-chunk = 16 cols (one MFMA-K), 2-deep sA ring 2x32KB (512 rows x
// 16 swizzled cols; slot = lh ^ ((row>>2)&1), element-verified vs staging).
// B path/slot functions r17-identical. Update/final: 16 threads/token.
// r18's direct-global-A is reverted (latency-serialized, 2x regression).
//
// d_out (float): [0, N*D) quantized_out; [N*D,+Q*N) indices; [+Q) losses
// d_ws: ecat f16[Q*K][512] | norms f32[Q*K]

typedef _Float16 f16;
typedef f16 f16x8 __attribute__((ext_vector_type(8)));
typedef float f32x16 __attribute__((ext_vector_type(16)));

constexpr int Dd = 256;
constexpr int Kk = 1024;
constexpr int Qq = 8;
constexpr int Nn = 16384;

__device__ inline void gload16(const f16* g, f16* l) {
    __builtin_amdgcn_global_load_lds(
        (const __attribute__((address_space(1))) unsigned int*)(const __attribute__((address_space(1))) f16*)g,
        (__attribute__((address_space(3))) unsigned int*)(__attribute__((address_space(3))) f16*)l,
        16, 0, 0);
}

// ---- build ecat[Q*K][512] = [eh|el] + squared norms, from fp32 codebooks ----
__global__ __launch_bounds__(256) void build_ecat(const float* __restrict__ cb,
                                                  f16* __restrict__ ecat,
                                                  float* __restrict__ norms) {
    int row = blockIdx.x * 8 + (threadIdx.x >> 5);
    int p = threadIdx.x & 31;
    const float* s = cb + (size_t)row * Dd + p * 8;
    f16x8 hi, lo;
    float sq = 0.f;
#pragma unroll
    for (int j = 0; j < 8; ++j) {
        float v = s[j];
        f16 h = (f16)v;
        hi[j] = h; lo[j] = (f16)(v - (float)h);
        sq = fmaf(v, v, sq);
    }
    *(f16x8*)(ecat + (size_t)row * 512 + p * 8) = hi;
    *(f16x8*)(ecat + (size_t)row * 512 + 256 + p * 8) = lo;
#pragma unroll
    for (int off = 16; off >= 1; off >>= 1) sq += __shfl_down(sq, off, 32);
    if (p == 0) norms[row] = sq;
}

// ---- the whole RVQ, one launch: block = 64 tokens through all 8 layers ----
__global__ __launch_bounds__(1024, 4) void rvq_kernel(
    const float* __restrict__ x,      // [N][256]
    const float* __restrict__ cbs,    // [Q][K][256] fp32
    const f16* __restrict__ ecat,     // [Q*K][512]
    const float* __restrict__ norms,  // [Q*K]
    float* __restrict__ outq,         // d_out [N][256]
    float* __restrict__ idxs,         // d_out [Q][N] (as float)
    float* __restrict__ losses)       // d_out [Q]
{
    __shared__ f16 sA[2][16384];      // ring2: 512 rows x 16 cols, eh | el(+8192)
    __shared__ f16 sB[32768];         // 8 sub-tiles [64r][32c] xh; +16384 xl
    __shared__ float smn[1024];
    __shared__ float2 smg[8][64];
    __shared__ int bestk[64];
    __shared__ float lred[16];

    const int tid = threadIdx.x;
    const int w = tid >> 6, l = tid & 63;
    const int l32 = l & 31, lh = l >> 5;
    const int cs = w >> 1;            // code slice 0..7 (64 codes per pass)
    const int wt = w & 1;             // token half 0..1 (32 tokens)
    const int tbase = blockIdx.x * 64;
    const int ut = tid >> 4, h = tid & 15;   // token 0..63, 16-dim group 0..15
    const int grow = tbase + ut;

    // A ds_read offsets (f16 units): row ra, slot = lh ^ ((ra>>2)&1)
    int offA[2];
#pragma unroll
    for (int m = 0; m < 2; ++m) {
        int ra = cs * 64 + m * 32 + l32;
        offA[m] = ra * 16 + ((lh ^ ((ra >> 2) & 1)) * 8);
    }
    // B ds_read offsets (r17): slot = (kh*2+lh) ^ ((row>>3)&3) ^ (c&3)
    int rbh[4][2];
#pragma unroll
    for (int cc = 0; cc < 4; ++cc)
#pragma unroll
        for (int kh = 0; kh < 2; ++kh) {
            int row = wt * 32 + l32;
            rbh[cc][kh] = row * 32 + ((((kh * 2 + lh) ^ ((row >> 3) & 3)) ^ cc) * 8);
        }

    // Staging geometry: thread t -> granule t (row t>>1, slot t&1);
    // source col-half pre-swizzled: ch = (t&1) ^ ((t>>3)&1).
    const int ch8 = (((tid & 1) ^ ((tid >> 3) & 1))) * 8;

    float r[16];   // residual: token ut, dims h*16 .. h*16+15

#define STAGE(P, PP, HC) do { \
        const f16* ga_ = ecat + ((size_t)q * Kk + (PP) * 512 + (tid >> 1)) * 512 + (HC) * 16 + ch8; \
        gload16(ga_,       &sA[P][tid * 8]); \
        gload16(ga_ + 256, &sA[P][8192 + tid * 8]); \
    } while (0)

#pragma unroll 1
    for (int q = 0; q < Qq; ++q) {
        // prestage (pass 0, half-chunk 0) -> buf 0; hides under update phase
        STAGE(0, 0, 0);

        // ---- update phase (residual in registers) ----
        float lp = 0.f;
        if (q == 0) {
            const float4* xs = (const float4*)(x + (size_t)grow * Dd + h * 16);
#pragma unroll
            for (int jv = 0; jv < 4; ++jv) {
                float4 v = xs[jv];
                r[jv * 4 + 0] = v.x; r[jv * 4 + 1] = v.y;
                r[jv * 4 + 2] = v.z; r[jv * 4 + 3] = v.w;
            }
        } else {
            const int k = bestk[ut];
            const float4* e4 = (const float4*)(cbs + ((size_t)(q - 1) * Kk + k) * Dd + h * 16);
#pragma unroll
            for (int jv = 0; jv < 4; ++jv) {
                float4 v = e4[jv];
                r[jv * 4 + 0] -= v.x; r[jv * 4 + 1] -= v.y;
                r[jv * 4 + 2] -= v.z; r[jv * 4 + 3] -= v.w;
            }
#pragma unroll
            for (int j = 0; j < 16; ++j) lp = fmaf(r[j], r[j], lp);
            if (h == 0) idxs[(size_t)(q - 1) * Nn + grow] = (float)k;
#pragma unroll
            for (int off = 32; off >= 1; off >>= 1) lp += __shfl_down(lp, off);
            if (l == 0) lred[w] = lp;
        }
        // ---- build B tile: thread covers token ut, dims h*16..+16 ----
        //      subtile st = h>>1; quad qq = (h&1)*2 + j (j compile-time);
        //      slot = qq ^ s ^ (st&3)  (matches reader; r17-verified family)
        {
            const int s = (ut >> 3) & 3;
            const int st = h >> 1;
#pragma unroll
            for (int j = 0; j < 2; ++j) {
                const int qq = (h & 1) * 2 + j;
                f16x8 hi, lo;
#pragma unroll
                for (int j2 = 0; j2 < 8; ++j2) {
                    float v = 2.f * r[j * 8 + j2];
                    f16 hv = (f16)v;
                    hi[j2] = hv; lo[j2] = (f16)(v - (float)hv);
                }
                int a = st * 2048 + ut * 32 + (((qq ^ s) ^ (st & 3)) & 3) * 8;
                *(f16x8*)&sB[a] = hi;
                *(f16x8*)&sB[16384 + a] = lo;
            }
        }
        smn[tid] = norms[q * Kk + tid];
        __syncthreads();   // full drain: sB writes, prestaged A, global stores
        if (q > 0 && tid == 0) {
            float s2 = 0.f;
#pragma unroll
            for (int i = 0; i < 16; ++i) s2 += lred[i];
            atomicAdd(losses + q - 1, s2 * (1.0f / ((float)Nn * (float)Dd)));
        }

        // ---- GEMM: 2 passes x 512 codes x 16 half-chunks ----
        float bv = -3.4e38f; int bi = 0;
#pragma unroll 1
        for (int p = 0; p < 2; ++p) {
            f32x16 acc[2] = {};
#pragma unroll
            for (int hc = 0; hc < 16; ++hc) {
                const int P = hc & 1;               // (p*16+hc)&1 == hc&1
                if (hc < 15)            STAGE(P ^ 1, p, hc + 1);
                else if (p == 0)        STAGE(P ^ 1, 1, 0);
                const int c = hc >> 1, kh = hc & 1;
                f16x8 a0 = *(const f16x8*)&sA[P][offA[0]];
                f16x8 a1 = *(const f16x8*)&sA[P][offA[1]];
                f16x8 bh = *(const f16x8*)&sB[c * 2048 + rbh[c & 3][kh]];
                f16x8 bl = *(const f16x8*)&sB[16384 + c * 2048 + rbh[c & 3][kh]];
                f16x8 e0 = *(const f16x8*)&sA[P][8192 + offA[0]];
                f16x8 e1 = *(const f16x8*)&sA[P][8192 + offA[1]];
                __builtin_amdgcn_s_setprio(1);
                acc[0] = __builtin_amdgcn_mfma_f32_32x32x16_f16(a0, bh, acc[0], 0, 0, 0);
                acc[1] = __builtin_amdgcn_mfma_f32_32x32x16_f16(a1, bh, acc[1], 0, 0, 0);
                acc[0] = __builtin_amdgcn_mfma_f32_32x32x16_f16(a0, bl, acc[0], 0, 0, 0);
                acc[1] = __builtin_amdgcn_mfma_f32_32x32x16_f16(a1, bl, acc[1], 0, 0, 0);
                acc[0] = __builtin_amdgcn_mfma_f32_32x32x16_f16(e0, bh, acc[0], 0, 0, 0);
                acc[1] = __builtin_amdgcn_mfma_f32_32x32x16_f16(e1, bh, acc[1], 0, 0, 0);
                __builtin_amdgcn_s_setprio(0);
                if (p * 16 + hc < 31)
                    asm volatile("s_waitcnt vmcnt(0)\n\ts_barrier" ::: "memory");
            }
            // epilogue: score = acc - |e|^2 ; ascending code order
#pragma unroll
            for (int m = 0; m < 2; ++m) {
#pragma unroll
                for (int rr = 0; rr < 16; ++rr) {
                    int cl = cs * 64 + m * 32 + (rr & 3) + 8 * (rr >> 2) + 4 * lh;
                    int cg = p * 512 + cl;
                    float v = acc[m][rr] - smn[cg];
                    if (v > bv) { bv = v; bi = cg; }
                }
            }
        }
        // ---- merge: lanes l<->l^32 (same token, other lh codes), then 8 slices ----
        {
            float ov = __shfl_xor(bv, 32);
            int oi = __shfl_xor(bi, 32);
            if (ov > bv || (ov == bv && oi < bi)) { bv = ov; bi = oi; }
            if (l < 32) smg[cs][wt * 32 + l32] = make_float2(bv, (float)bi);
            __syncthreads();
            if (tid < 64) {
                float2 r2 = smg[0][tid];
#pragma unroll
                for (int ww = 1; ww < 8; ++ww) {
                    float2 c2 = smg[ww][tid];
                    if (c2.x > r2.x || (c2.x == r2.x && c2.y < r2.y)) r2 = c2;
                }
                bestk[tid] = (int)r2.y;
            }
            __syncthreads();
        }
    }
#undef STAGE

    // ---- final: subtract e7, loss7, idx7, out = x - r8 ----
    {
        const int k = bestk[ut];
        const float4* e4 = (const float4*)(cbs + ((size_t)7 * Kk + k) * Dd + h * 16);
        float lp = 0.f;
#pragma unroll
        for (int jv = 0; jv < 4; ++jv) {
            float4 v = e4[jv];
            r[jv * 4 + 0] -= v.x; r[jv * 4 + 1] -= v.y;
            r[jv * 4 + 2] -= v.z; r[jv * 4 + 3] -= v.w;
        }
#pragma unroll
        for (int j = 0; j < 16; ++j) lp = fmaf(r[j], r[j], lp);
        const float4* xs = (const float4*)(x + (size_t)grow * Dd + h * 16);
        float4* os = (float4*)(outq + (size_t)grow * Dd + h * 16);
#pragma unroll
        for (int jv = 0; jv < 4; ++jv) {
            float4 xv = xs[jv];
            float4 o;
            o.x = xv.x - r[jv * 4 + 0]; o.y = xv.y - r[jv * 4 + 1];
            o.z = xv.z - r[jv * 4 + 2]; o.w = xv.w - r[jv * 4 + 3];
            os[jv] = o;
        }
        if (h == 0) idxs[(size_t)7 * Nn + grow] = (float)k;
#pragma unroll
        for (int off = 32; off >= 1; off >>= 1) lp += __shfl_down(lp, off);
        if (l == 0) lred[w] = lp;
        __syncthreads();
        if (tid == 0) {
            float s2 = 0.f;
#pragma unroll
            for (int i = 0; i < 16; ++i) s2 += lred[i];
            atomicAdd(losses + 7, s2 * (1.0f / ((float)Nn * (float)Dd)));
        }
    }
}

extern "C" void kernel_launch(void* const* d_in, const int* in_sizes, int n_in,
                              void* d_out, int out_size, void* d_ws, size_t ws_size,
                              hipStream_t stream) {
    const float* x   = (const float*)d_in[0];   // [N,D]
    const float* cbs = (const float*)d_in[1];   // [Q,K,D]
    float* out    = (float*)d_out;
    float* idxs   = out + (size_t)Nn * Dd;        // [Q*N]
    float* losses = idxs + (size_t)Qq * Nn;       // [Q]

    f16* ecat    = (f16*)d_ws;                          // [Q*K][512]
    float* norms = (float*)(ecat + (size_t)Qq * Kk * 512);  // [Q*K]

    hipMemsetAsync(losses, 0, Qq * sizeof(float), stream);
    build_ecat<<<(Qq * Kk) / 8, 256, 0, stream>>>(cbs, ecat, norms);
    rvq_kernel<<<Nn / 64, 1024, 0, stream>>>(x, cbs, ecat, norms,
                                             out, idxs, losses);
}